// Round 2
// baseline (443.719 us; speedup 1.0000x reference)
//
#include <hip/hip_runtime.h>

// CRC-24 encoder: out = [bits | parity(bits @ G mod 2)]
// BATCH=16384 rows, K=4096 bits/row, 24 CRC bits, OUTW=4120.
// Memory-bound: ~538 MB mandatory traffic -> ~90us floor at 6.3 TB/s.
//
// R2: no LDS (16KB gm table lives in L1), nontemporal streaming loads/stores,
// vectorized parity store. One wave per row.

constexpr int K       = 4096;
constexpr int CRC_LEN = 24;
constexpr int OUTW    = K + CRC_LEN;   // 4120 floats, 16480 B (16B-aligned rows)
constexpr int BATCH   = 16384;

typedef float  vfloat4 __attribute__((ext_vector_type(4)));
typedef unsigned int vuint4 __attribute__((ext_vector_type(4)));

// Pack each g_mat row (24 floats of 0/1) into one 24-bit word -> d_ws (16 KB).
__global__ void pack_gmat_kernel(const float* __restrict__ g,
                                 unsigned int* __restrict__ gm) {
    int i = blockIdx.x * blockDim.x + threadIdx.x;
    if (i < K) {
        unsigned int w = 0u;
        #pragma unroll
        for (int j = 0; j < CRC_LEN; ++j)
            w |= (g[i * CRC_LEN + j] != 0.0f ? 1u : 0u) << j;
        gm[i] = w;
    }
}

// One wave (64 lanes) per row; 4 waves per 256-thread block.
__global__ __launch_bounds__(256) void crc_encode_kernel(
        const float* __restrict__ in,
        const unsigned int* __restrict__ gm,
        float* __restrict__ out) {
    const int t    = threadIdx.x;
    const int lane = t & 63;
    const int row  = blockIdx.x * 4 + (t >> 6);

    const vfloat4* in4  = (const vfloat4*)(in + (size_t)row * K);
    const vuint4*  gm4  = (const vuint4*)gm;               // 16 KB, L1-resident
    vfloat4*       out4 = (vfloat4*)(out + (size_t)row * OUTW);

    unsigned int acc = 0u;
    #pragma unroll
    for (int it = 0; it < K / 256; ++it) {
        const int v = it * 64 + lane;                      // float4 index in row
        vfloat4 b = __builtin_nontemporal_load(&in4[v]);   // streaming, no reuse
        vuint4  w = gm4[v];                                // cached, heavy reuse
        __builtin_nontemporal_store(b, &out4[v]);          // fused concat copy
        acc ^= (b.x != 0.0f) ? w.x : 0u;                   // v_cmp + v_cndmask + v_xor
        acc ^= (b.y != 0.0f) ? w.y : 0u;
        acc ^= (b.z != 0.0f) ? w.z : 0u;
        acc ^= (b.w != 0.0f) ? w.w : 0u;
    }

    // 64-lane XOR butterfly: every lane ends with the full parity word.
    #pragma unroll
    for (int off = 32; off >= 1; off >>= 1)
        acc ^= __shfl_xor(acc, off);

    // 24 parity floats as 6 float4 stores (lanes 0..5).
    if (lane < CRC_LEN / 4) {
        vfloat4 p;
        p.x = (float)((acc >> (4 * lane + 0)) & 1u);
        p.y = (float)((acc >> (4 * lane + 1)) & 1u);
        p.z = (float)((acc >> (4 * lane + 2)) & 1u);
        p.w = (float)((acc >> (4 * lane + 3)) & 1u);
        __builtin_nontemporal_store(p, &out4[K / 4 + lane]);
    }
}

extern "C" void kernel_launch(void* const* d_in, const int* in_sizes, int n_in,
                              void* d_out, int out_size, void* d_ws, size_t ws_size,
                              hipStream_t stream) {
    const float* bits = (const float*)d_in[0];   // (16384, 4096) float32 of 0/1
    const float* g    = (const float*)d_in[1];   // (4096, 24)   float32 of 0/1
    float* out        = (float*)d_out;           // (16384, 4120) float32
    unsigned int* gm  = (unsigned int*)d_ws;     // 4096 packed words (16 KB)

    pack_gmat_kernel<<<K / 256, 256, 0, stream>>>(g, gm);
    crc_encode_kernel<<<BATCH / 4, 256, 0, stream>>>(bits, gm, out);
}